// Round 19
// baseline (208.229 us; speedup 1.0000x reference)
//
#include <hip/hip_runtime.h>
#include <math.h>

// Problem constants (B=2, T=8, H=W=56, C=128, heads=8, hd=16, WS=7, nh=nw=8)
constexpr int H_   = 56;
constexpr int HW_  = 56 * 56;          // 3136
constexpr int NPIX = 8 * HW_;          // 25088 (per batch)
constexpr int SLAB = 128 * HW_ * 16;   // floats per q/k/v buffer
constexpr int CWST = 52;               // cwpk row stride (u32)

typedef __attribute__((ext_vector_type(8))) short bf16x8;
typedef __attribute__((ext_vector_type(4))) float f32x4;
typedef __attribute__((ext_vector_type(4))) unsigned int u32x4;

__device__ __forceinline__ unsigned short f2bf(float x) {
  unsigned int u = __float_as_uint(x);
  unsigned int r = (u + 0x7fffu + ((u >> 16) & 1u)) >> 16;
  return (unsigned short)r;
}
__device__ __forceinline__ float bf2f(unsigned short h) {
  return __uint_as_float(((unsigned int)h) << 16);
}

// ---------------------------------------------------------------------------
// K1 v2: QKV GEMM via MFMA split-bf16 (3-product), fused l2norm + scatter.
// fp32 SIMD path was the wall (83us at 50% VALU; 157TF floor = 31us). MFMA
// at ~2PF effective turns this memory-bound (~150MB -> ~25-40us).
//  - 4 waves (2x2), wave sub-tile 64x64, 16x16x32 tiles, K in 2 LDS halves.
//  - X staged as packed bf16 hi|lo<<16 u32 [128][68] (34.8KB, <=4-way conf).
//  - W fragments converted in-register (W is 192KB, L2-hot).
//  - Epilogue: per-(pixel,head) sum of squares via shfl_xor(1,2,4,8) over the
//    lane&15 group (C/D col dim = the head's 16 channels), rsqrt, scatter.
// ---------------------------------------------------------------------------
__global__ __launch_bounds__(256) void qkv_mfma(
    const float* __restrict__ X, const float* __restrict__ Wt,
    float* __restrict__ Yq, float* __restrict__ Yk, float* __restrict__ Yv)
{
  __shared__ unsigned int xS[128 * 68];   // 34816 B
  const int tid = threadIdx.x;
  const int wave = tid >> 6, lane = tid & 63;
  const int lg = lane >> 4, lr = lane & 15;
  const int wm = wave >> 1, wn = wave & 1;
  const int mbase = blockIdx.x * 128;
  const int nt = blockIdx.y;
  const float* Wp = Wt + (size_t)nt * (128 * 128);
  float* Ybase = (nt == 0) ? Yq : ((nt == 1) ? Yk : Yv);

  f32x4 acc[4][4];
#pragma unroll
  for (int mt = 0; mt < 4; ++mt)
#pragma unroll
    for (int ct = 0; ct < 4; ++ct) acc[mt][ct] = (f32x4)0.f;

#pragma unroll
  for (int kh = 0; kh < 2; ++kh) {
    if (kh) __syncthreads();            // xS reuse
    // ---- stage X k-half as packed hi/lo u32 (8 chunks/thread) ----
#pragma unroll
    for (int c = 0; c < 8; ++c) {
      const int chunk = c * 256 + tid;  // 0..2047
      const int row = chunk >> 4;
      const int cc = chunk & 15;
      f32x4 v = *(const f32x4*)(X + (size_t)(mbase + row) * 128 + kh * 64 + cc * 4);
      unsigned int pk[4];
#pragma unroll
      for (int e = 0; e < 4; ++e) {
        unsigned short hb = f2bf(v[e]);
        unsigned short lb = f2bf(v[e] - bf2f(hb));
        pk[e] = (unsigned)hb | ((unsigned)lb << 16);
      }
      *(u32x4*)&xS[row * 68 + cc * 4] = *(const u32x4*)pk;
    }
    __syncthreads();

#pragma unroll
    for (int ks2 = 0; ks2 < 2; ++ks2) {
      // ---- A-fragments from staged xS ----
      bf16x8 ah[4], al[4];
#pragma unroll
      for (int mt = 0; mt < 4; ++mt) {
        const unsigned int* s = &xS[(wm * 64 + mt * 16 + lr) * 68 + ks2 * 32 + lg * 8];
        unsigned int u0[8];
        *(u32x4*)&u0[0] = *(const u32x4*)s;
        *(u32x4*)&u0[4] = *(const u32x4*)(s + 4);
        union { u32x4 uu; bf16x8 ss; } Hh, Ll;
#pragma unroll
        for (int p = 0; p < 4; ++p) {
          Hh.uu[p] = (u0[2*p] & 0xffffu) | (u0[2*p+1] << 16);
          Ll.uu[p] = (u0[2*p] >> 16) | (u0[2*p+1] & 0xffff0000u);
        }
        ah[mt] = Hh.ss;
        al[mt] = Ll.ss;
      }
      // ---- B-fragments from global W (convert in-register) ----
      bf16x8 bh[4], bl[4];
#pragma unroll
      for (int ct = 0; ct < 4; ++ct) {
        const float* wsrc = Wp + (size_t)(wn * 64 + ct * 16 + lr) * 128 + kh * 64 + ks2 * 32 + lg * 8;
        f32x4 w0 = *(const f32x4*)wsrc;
        f32x4 w1 = *(const f32x4*)(wsrc + 4);
        float wsv[8] = {w0.x, w0.y, w0.z, w0.w, w1.x, w1.y, w1.z, w1.w};
        union { u32x4 uu; bf16x8 ss; } Hh, Ll;
#pragma unroll
        for (int p = 0; p < 4; ++p) {
          unsigned short h0 = f2bf(wsv[2*p]),     h1 = f2bf(wsv[2*p+1]);
          unsigned short l0 = f2bf(wsv[2*p] - bf2f(h0)), l1 = f2bf(wsv[2*p+1] - bf2f(h1));
          Hh.uu[p] = (unsigned)h0 | ((unsigned)h1 << 16);
          Ll.uu[p] = (unsigned)l0 | ((unsigned)l1 << 16);
        }
        bh[ct] = Hh.ss;
        bl[ct] = Ll.ss;
      }
      // ---- MFMA 3-product ----
#pragma unroll
      for (int mt = 0; mt < 4; ++mt) {
#pragma unroll
        for (int ct = 0; ct < 4; ++ct) {
          acc[mt][ct] = __builtin_amdgcn_mfma_f32_16x16x32_bf16(ah[mt], bh[ct], acc[mt][ct], 0, 0, 0);
          acc[mt][ct] = __builtin_amdgcn_mfma_f32_16x16x32_bf16(ah[mt], bl[ct], acc[mt][ct], 0, 0, 0);
          acc[mt][ct] = __builtin_amdgcn_mfma_f32_16x16x32_bf16(al[mt], bh[ct], acc[mt][ct], 0, 0, 0);
        }
      }
    }
  }

  // ---- epilogue: l2norm per (pixel, head) + scatter to (BT, HW, 16) ----
#pragma unroll
  for (int mt = 0; mt < 4; ++mt) {
#pragma unroll
    for (int reg = 0; reg < 4; ++reg) {
      const int gpix = mbase + wm * 64 + mt * 16 + lg * 4 + reg;
      const int b = (gpix >= NPIX) ? 1 : 0;
      const int rem = gpix - b * NPIX;
      const int t = rem / HW_;
      const int sp = rem - t * HW_;
#pragma unroll
      for (int ct = 0; ct < 4; ++ct) {
        float val = acc[mt][ct][reg];
        float ss = val * val;
        ss += __shfl_xor(ss, 1);
        ss += __shfl_xor(ss, 2);
        ss += __shfl_xor(ss, 4);
        ss += __shfl_xor(ss, 8);
        float r = 1.f;
        if (nt < 2) r = 1.f / fmaxf(sqrtf(ss), 1e-12f);
        const int btq = (b * 8 + wn * 4 + ct) * 8 + t;
        Ybase[((size_t)btq * HW_ + sp) * 16 + lr] = val * r;
      }
    }
  }
}

// ---------------------------------------------------------------------------
// GEMM (fp32): kept for K3 proj only (in-place row-disjoint, bias).
// ---------------------------------------------------------------------------
template <int MODE>
__global__ __launch_bounds__(256, 3) void gemm128(
    const float* X, const float* __restrict__ Wt, const float* __restrict__ bias,
    float* __restrict__ Yq, float* __restrict__ Yk, float* __restrict__ Yv,
    float* Yout)
{
  __shared__ float xT[32][132];
  __shared__ float wT[32][132];
  const int tid = threadIdx.x;
  const int tx = tid & 15, ty = tid >> 4;
  const int mbase = blockIdx.x * 128;
  const float* Wp = Wt;

  float acc[8][8];
#pragma unroll
  for (int i = 0; i < 8; ++i)
#pragma unroll
    for (int j = 0; j < 8; ++j) acc[i][j] = 0.f;

  const int srow = tid >> 3;
  const int scol = (tid & 7) * 4;

  for (int kt = 0; kt < 4; ++kt) {
    if (kt) __syncthreads();
#pragma unroll
    for (int p = 0; p < 4; ++p) {
      int r = p * 32 + srow;
      float4 vx = *(const float4*)&X [(size_t)(mbase + r) * 128 + kt * 32 + scol];
      float4 vw = *(const float4*)&Wp[(size_t)r * 128 + kt * 32 + scol];
      xT[scol + 0][r] = vx.x; xT[scol + 1][r] = vx.y; xT[scol + 2][r] = vx.z; xT[scol + 3][r] = vx.w;
      wT[scol + 0][r] = vw.x; wT[scol + 1][r] = vw.y; wT[scol + 2][r] = vw.z; wT[scol + 3][r] = vw.w;
    }
    __syncthreads();
#pragma unroll 4
    for (int c = 0; c < 32; ++c) {
      float4 a0 = *(const float4*)&xT[c][tx * 4];
      float4 a1 = *(const float4*)&xT[c][64 + tx * 4];
      float4 b0 = *(const float4*)&wT[c][ty * 4];
      float4 b1 = *(const float4*)&wT[c][64 + ty * 4];
      float a[8] = {a0.x, a0.y, a0.z, a0.w, a1.x, a1.y, a1.z, a1.w};
      float b[8] = {b0.x, b0.y, b0.z, b0.w, b1.x, b1.y, b1.z, b1.w};
#pragma unroll
      for (int i = 0; i < 8; ++i)
#pragma unroll
        for (int j = 0; j < 8; ++j) acc[i][j] += a[i] * b[j];
    }
  }

  {
    float4 bb0 = *(const float4*)&bias[ty * 4];
    float4 bb1 = *(const float4*)&bias[64 + ty * 4];
#pragma unroll
    for (int i = 0; i < 8; ++i) {
      int gpix = mbase + ((i < 4) ? (tx * 4 + i) : (64 + tx * 4 + (i - 4)));
      float* dst = Yout + (size_t)gpix * 128;
      *(float4*)&dst[ty * 4]      = make_float4(acc[i][0]+bb0.x, acc[i][1]+bb0.y, acc[i][2]+bb0.z, acc[i][3]+bb0.w);
      *(float4*)&dst[64 + ty * 4] = make_float4(acc[i][4]+bb1.x, acc[i][5]+bb1.y, acc[i][6]+bb1.z, acc[i][7]+bb1.w);
    }
  }
}

// ---------------------------------------------------------------------------
// K2a v5 (R18 verbatim): dense correlation with batched LDS reads.
// ---------------------------------------------------------------------------
__global__ __launch_bounds__(256) void corr_dense(
    const float* __restrict__ qn, const float* __restrict__ kn,
    const float* __restrict__ pos1,
    unsigned int* __restrict__ cwpk, float* __restrict__ diib)
{
  __shared__ float kS[10 * 1120];    // 10 rows x 56 px x 20 floats = 44800 B
  const int bid = blockIdx.x;        // 1792 = 8 xcd * 16 bt * 14 strips
  const int xcd = bid & 7;
  const int j = bid >> 3;            // 0..223
  const int g = j / 14;
  const int strip = j - g * 14;
  const int bt = xcd * 16 + g;
  const int h0 = strip * 4;
  const int t = bt & 7;
  const int btk = bt - t + ((t < 7) ? (t + 1) : 7);
  const float* qb = qn + (size_t)bt  * (HW_ * 16);
  const float* kb = kn + (size_t)btk * (HW_ * 16);
  const int tid = threadIdx.x;

  for (int idx = tid; idx < 2240; idx += 256) {
    int r = idx / 224;
    int c = idx - r * 224;
    int hh = h0 - 3 + r;
    f32x4 v = (f32x4)0.f;
    if ((unsigned)hh < 56u)
      v = *(const f32x4*)(kb + (size_t)(hh * 56) * 16 + c * 4);
    *(f32x4*)&kS[r * 1120 + (c >> 2) * 20 + (c & 3) * 4] = v;
  }
  __syncthreads();

  if (tid < 224) {
    const int py = tid / 56;
    const int h = h0 + py;
    const int w = tid - py * 56;
    const f32x4* qp = (const f32x4*)(qb + (size_t)(h * 56 + w) * 16);
    f32x4 q0 = qp[0], q1 = qp[1], q2 = qp[2], q3 = qp[3];
    const int ridx = (h >> 3) * 7 + (w >> 3);
    const float* p1r = pos1 + ridx * 49;
    unsigned int* outr = cwpk + (size_t)(bt * HW_ + h * 56 + w) * CWST;
    float dii = 0.f;
#pragma unroll
    for (int d4 = 0; d4 < 12; ++d4) {
      f32x4 kv[4][4];
#pragma unroll
      for (int e = 0; e < 4; ++e) {
        const int d = d4 * 4 + e;
        const int du = d / 7, dv = d % 7;
        const int ww = w + dv - 3;
        const int wc = ww < 0 ? 0 : (ww > 55 ? 55 : ww);
        const float* kp = &kS[(py + du) * 1120 + wc * 20];
        kv[e][0] = *(const f32x4*)kp;
        kv[e][1] = *(const f32x4*)(kp + 4);
        kv[e][2] = *(const f32x4*)(kp + 8);
        kv[e][3] = *(const f32x4*)(kp + 12);
      }
      unsigned int pk[4];
#pragma unroll
      for (int e = 0; e < 4; ++e) {
        const int d = d4 * 4 + e;
        const int dv = d % 7;
        const int ww = w + dv - 3;
        f32x4 a4 = q0 * kv[e][0] + q1 * kv[e][1] + q2 * kv[e][2] + q3 * kv[e][3];
        float pd = (a4.x + a4.y) + (a4.z + a4.w);
        pd = ((unsigned)ww < 56u) ? pd : 0.f;
        const float val = pd + p1r[d];
        dii += val * val;
        unsigned short hb = f2bf(val);
        unsigned short lb = f2bf(val - bf2f(hb));
        pk[e] = (unsigned)hb | ((unsigned)lb << 16);
      }
      *(u32x4*)(outr + d4 * 4) = *(const u32x4*)pk;
    }
    {
      const int ww = w + 3;
      const int wc = ww > 55 ? 55 : ww;
      const float* kp = &kS[(py + 6) * 1120 + wc * 20];
      f32x4 k0 = *(const f32x4*)kp;
      f32x4 k1 = *(const f32x4*)(kp + 4);
      f32x4 k2 = *(const f32x4*)(kp + 8);
      f32x4 k3 = *(const f32x4*)(kp + 12);
      f32x4 a4 = q0 * k0 + q1 * k1 + q2 * k2 + q3 * k3;
      float pd = (a4.x + a4.y) + (a4.z + a4.w);
      pd = ((unsigned)ww < 56u) ? pd : 0.f;
      const float val = pd + p1r[48];
      dii += val * val;
      unsigned short hb = f2bf(val);
      unsigned short lb = f2bf(val - bf2f(hb));
      outr[48] = (unsigned)hb | ((unsigned)lb << 16);
    }
    diib[bt * HW_ + h * 56 + w] = dii;
  }
}

// ---------------------------------------------------------------------------
// K2b: MFMA window attention (R13/R18 verbatim).
// ---------------------------------------------------------------------------
__global__ __launch_bounds__(64, 2) void attn_mfma(
    const float* __restrict__ qn, const float* __restrict__ vv,
    const unsigned int* __restrict__ cwpk, const float* __restrict__ diib,
    const float* __restrict__ pos2, float* __restrict__ mid)
{
  __shared__ __align__(16) unsigned char smem[7808];
  unsigned short* Pb   = (unsigned short*)smem;       // [49][72] bf16 (7056 B)
  float*          mi_s = (float*)(smem + 7104);       // [49]
  float*          scm  = (float*)(smem + 7300);       // [49]
  float*          sca  = (float*)(smem + 7500);       // [49]

  const int lane = threadIdx.x;
  const int lg = lane >> 4;
  const int lr = lane & 15;
  const int bid = blockIdx.x;
  const int xcd = bid & 7;
  const int j = bid >> 3;
  const int bt = xcd * 16 + (j >> 6);
  const int win = j & 63;
  const int wy = win >> 3;
  const int wx = win & 7;
  const float* qb = qn + (size_t)bt * (HW_ * 16);
  const float* vb = vv + (size_t)bt * (HW_ * 16);
  const unsigned int* cwb = cwpk + (size_t)bt * HW_ * CWST;
  const float* dib = diib + (size_t)bt * HW_;

  const bool rowok = (lane < 49);
  const int il = rowok ? lane : 48;

  float xv[2][8];
#pragma unroll
  for (int ks = 0; ks < 2; ++ks) {
#pragma unroll
    for (int e = 0; e < 8; ++e) {
      int k = ks * 32 + lg * 8 + e;
      int kc2 = (k < 49) ? k : 0;
      int ka = (kc2 * 37) >> 8;
      int kb2 = kc2 - ka * 7;
      float x = vb[(size_t)((ka * 8 + wy) * 56 + (kb2 * 8 + wx)) * 16 + lr];
      xv[ks][e] = (k < 49) ? x : 0.f;
    }
  }

  {
    const int ia = (il * 37) >> 8;
    const int ib = il - ia * 7;
    float dii = dib[(ia * 8 + wy) * 56 + (ib * 8 + wx)];
    float md = dii;
#pragma unroll
    for (int o = 32; o >= 1; o >>= 1) md = fmaxf(md, __shfl_xor(md, o));
    if (rowok) mi_s[il] = sqrtf(dii * md);
  }

  bf16x8 ah[4][2], al[4][2];
#pragma unroll
  for (int half = 0; half < 2; ++half) {
    u32x4 raw[2][2][2];
#pragma unroll
    for (int u = 0; u < 2; ++u) {
      const int tt2 = half * 2 + u;
      const int row = tt2 * 16 + lr;
      const int rowc = (row < 49) ? row : 0;
      const int a2 = (rowc * 37) >> 8;
      const int b3 = rowc - a2 * 7;
      const unsigned int* src = cwb + (size_t)((a2 * 8 + wy) * 56 + (b3 * 8 + wx)) * CWST;
#pragma unroll
      for (int ks = 0; ks < 2; ++ks) {
        const int cb = ks * 32 + lg * 8;
        raw[u][ks][0] = *(const u32x4*)(src + cb);
        raw[u][ks][1] = *(const u32x4*)(src + cb + 4);
      }
    }
#pragma unroll
    for (int u = 0; u < 2; ++u) {
      const int tt2 = half * 2 + u;
      const int row = tt2 * 16 + lr;
      const bool rv = (row < 49);
#pragma unroll
      for (int ks = 0; ks < 2; ++ks) {
        const int cb = ks * 32 + lg * 8;
        unsigned int u0[8];
        *(u32x4*)&u0[0] = raw[u][ks][0];
        *(u32x4*)&u0[4] = raw[u][ks][1];
#pragma unroll
        for (int e = 0; e < 8; ++e)
          if (!rv || (cb + e) >= 49) u0[e] = 0u;
        union { u32x4 uu; bf16x8 s; } Hh, Ll;
#pragma unroll
        for (int p = 0; p < 4; ++p) {
          Hh.uu[p] = (u0[2*p] & 0xffffu) | (u0[2*p+1] << 16);
          Ll.uu[p] = (u0[2*p] >> 16) | (u0[2*p+1] & 0xffff0000u);
        }
        ah[tt2][ks] = Hh.s;
        al[tt2][ks] = Ll.s;
      }
    }
  }

#pragma unroll
  for (int rt = 0; rt < 4; ++rt) {
    f32x4 C[4];
#pragma unroll
    for (int ct = 0; ct < 4; ++ct) C[ct] = (f32x4)0.f;
#pragma unroll
    for (int ks = 0; ks < 2; ++ks) {
#pragma unroll
      for (int ct = 0; ct < 4; ++ct) {
        C[ct] = __builtin_amdgcn_mfma_f32_16x16x32_bf16(ah[rt][ks], ah[ct][ks], C[ct], 0, 0, 0);
        C[ct] = __builtin_amdgcn_mfma_f32_16x16x32_bf16(ah[rt][ks], al[ct][ks], C[ct], 0, 0, 0);
        C[ct] = __builtin_amdgcn_mfma_f32_16x16x32_bf16(al[rt][ks], ah[ct][ks], C[ct], 0, 0, 0);
      }
    }
#pragma unroll
    for (int reg = 0; reg < 4; ++reg) {
      int row = rt * 16 + lg * 4 + reg;
      float m = mi_s[(row < 49) ? row : 0];
#pragma unroll
      for (int ct = 0; ct < 4; ++ct) {
        float p = __expf(C[ct][reg] - m);
        if (row < 49) Pb[row * 72 + ct * 16 + lr] = f2bf(p);
      }
    }
  }
  asm volatile("" ::: "memory");

  if (rowok) {
    const u32x4* pr = (const u32x4*)(Pb + il * 72);
    unsigned int uu[28];
#pragma unroll
    for (int w = 0; w < 7; ++w) *(u32x4*)&uu[4*w] = pr[w];
    float s = 0.f;
#pragma unroll
    for (int w = 0; w < 24; ++w)
      s += bf2f((unsigned short)(uu[w] & 0xffffu)) + bf2f((unsigned short)(uu[w] >> 16));
    s += bf2f((unsigned short)(uu[24] & 0xffffu));
    scm[il] = 0.5f / s;
  }

  bf16x8 vfh[2], vfl[2];
#pragma unroll
  for (int ks = 0; ks < 2; ++ks) {
    union { u32x4 u; bf16x8 s; } Hh, Ll;
#pragma unroll
    for (int p = 0; p < 4; ++p) {
      unsigned short h0 = f2bf(xv[ks][2*p]);
      unsigned short h1 = f2bf(xv[ks][2*p+1]);
      unsigned short l0 = f2bf(xv[ks][2*p]   - bf2f(h0));
      unsigned short l1 = f2bf(xv[ks][2*p+1] - bf2f(h1));
      Hh.u[p] = (unsigned int)h0 | ((unsigned int)h1 << 16);
      Ll.u[p] = (unsigned int)l0 | ((unsigned int)l1 << 16);
    }
    vfh[ks] = Hh.s;
    vfl[ks] = Ll.s;
  }

  f32x4 om[4];
#pragma unroll
  for (int rt = 0; rt < 4; ++rt) om[rt] = (f32x4)0.f;
#pragma unroll
  for (int ks = 0; ks < 2; ++ks) {
#pragma unroll
    for (int rt = 0; rt < 4; ++rt) {
      int row = rt * 16 + lr;
      int rowc = (row < 49) ? row : 0;
      bf16x8 pa = *(const bf16x8*)(Pb + rowc * 72 + ks * 32 + lg * 8);
      om[rt] = __builtin_amdgcn_mfma_f32_16x16x32_bf16(pa, vfh[ks], om[rt], 0, 0, 0);
      om[rt] = __builtin_amdgcn_mfma_f32_16x16x32_bf16(pa, vfl[ks], om[rt], 0, 0, 0);
    }
  }
  asm volatile("s_waitcnt lgkmcnt(0)" ::: "memory");

  bf16x8 qf[4];
#pragma unroll
  for (int half = 0; half < 2; ++half) {
    f32x4 qa_[2], qb_[2], pa_[2], pb_[2];
#pragma unroll
    for (int u = 0; u < 2; ++u) {
      const int tt2 = half * 2 + u;
      int row = tt2 * 16 + lr;
      int rowc = (row < 49) ? row : 0;
      int a2 = (rowc * 37) >> 8;
      int b3 = rowc - a2 * 7;
      const int co = (lg & 1) * 8;
      const float* qsrc = qb + (size_t)((a2 * 8 + wy) * 56 + (b3 * 8 + wx)) * 16 + co;
      qa_[u] = *(const f32x4*)qsrc;
      qb_[u] = *(const f32x4*)(qsrc + 4);
      const float* p2 = pos2 + rowc * 16 + co;
      pa_[u] = *(const f32x4*)p2;
      pb_[u] = *(const f32x4*)(p2 + 4);
    }
#pragma unroll
    for (int u = 0; u < 2; ++u) {
      const int tt2 = half * 2 + u;
      int row = tt2 * 16 + lr;
      f32x4 w0 = qa_[u] + pa_[u], w1 = qb_[u] + pb_[u];
      float ws[8] = {w0.x, w0.y, w0.z, w0.w, w1.x, w1.y, w1.z, w1.w};
      const bool zv = (row >= 49) || (lg >= 2);
      union { u32x4 u4; bf16x8 s; } Q;
#pragma unroll
      for (int p = 0; p < 4; ++p) {
        unsigned int v = (unsigned)f2bf(ws[2*p]) | ((unsigned)f2bf(ws[2*p+1]) << 16);
        Q.u4[p] = zv ? 0u : v;
      }
      qf[tt2] = Q.s;
    }
  }

#pragma unroll
  for (int rt = 0; rt < 4; ++rt) {
    f32x4 Ca[4];
#pragma unroll
    for (int ct = 0; ct < 4; ++ct) Ca[ct] = (f32x4)0.f;
#pragma unroll
    for (int ct = 0; ct < 4; ++ct)
      Ca[ct] = __builtin_amdgcn_mfma_f32_16x16x32_bf16(qf[rt], qf[ct], Ca[ct], 0, 0, 0);
#pragma unroll
    for (int reg = 0; reg < 4; ++reg) {
      int row = rt * 16 + lg * 4 + reg;
#pragma unroll
      for (int ct = 0; ct < 4; ++ct) {
        float p = __expf(Ca[ct][reg]);
        if (row < 49) Pb[row * 72 + ct * 16 + lr] = f2bf(p);
      }
    }
  }
  asm volatile("" ::: "memory");

  if (rowok) {
    const u32x4* pr = (const u32x4*)(Pb + il * 72);
    unsigned int uu[28];
#pragma unroll
    for (int w = 0; w < 7; ++w) *(u32x4*)&uu[4*w] = pr[w];
    float s = 0.f;
#pragma unroll
    for (int w = 0; w < 24; ++w)
      s += bf2f((unsigned short)(uu[w] & 0xffffu)) + bf2f((unsigned short)(uu[w] >> 16));
    s += bf2f((unsigned short)(uu[24] & 0xffffu));
    sca[il] = 0.5f / s;
  }

  f32x4 oa[4];
#pragma unroll
  for (int rt = 0; rt < 4; ++rt) oa[rt] = (f32x4)0.f;
#pragma unroll
  for (int ks = 0; ks < 2; ++ks) {
#pragma unroll
    for (int rt = 0; rt < 4; ++rt) {
      int row = rt * 16 + lr;
      int rowc = (row < 49) ? row : 0;
      bf16x8 pa = *(const bf16x8*)(Pb + rowc * 72 + ks * 32 + lg * 8);
      oa[rt] = __builtin_amdgcn_mfma_f32_16x16x32_bf16(pa, vfh[ks], oa[rt], 0, 0, 0);
      oa[rt] = __builtin_amdgcn_mfma_f32_16x16x32_bf16(pa, vfl[ks], oa[rt], 0, 0, 0);
    }
  }

  {
    int b = bt >> 6, e = (bt >> 3) & 7, tt = bt & 7;
    size_t obase = ((size_t)(b * NPIX + tt * HW_)) * 128 + e * 16 + lr;
#pragma unroll
    for (int rt = 0; rt < 4; ++rt) {
#pragma unroll
      for (int reg = 0; reg < 4; ++reg) {
        int row = rt * 16 + lg * 4 + reg;
        if (row < 49) {
          float o = om[rt][reg] * scm[row] + oa[rt][reg] * sca[row];
          int a2 = (row * 37) >> 8;
          int b3 = row - a2 * 7;
          mid[obase + (size_t)((a2 * 8 + wy) * 56 + (b3 * 8 + wx)) * 128] = o;
        }
      }
    }
  }
}

// ---------------------------------------------------------------------------
extern "C" void kernel_launch(void* const* d_in, const int* in_sizes, int n_in,
                              void* d_out, int out_size, void* d_ws, size_t ws_size,
                              hipStream_t stream) {
  (void)in_sizes; (void)n_in; (void)out_size; (void)ws_size;
  const float* x      = (const float*)d_in[0];
  const float* qkv_w  = (const float*)d_in[1];
  const float* proj_w = (const float*)d_in[2];
  const float* proj_b = (const float*)d_in[3];
  const float* pos1   = (const float*)d_in[4];
  const float* pos2   = (const float*)d_in[5];
  float* out = (float*)d_out;

  float* qn = (float*)d_ws;                               // SLAB f32
  float* kc = qn + SLAB;                                  // SLAB f32
  float* vv = kc + SLAB;                                  // SLAB f32
  unsigned int* cwpk = (unsigned int*)(vv + SLAB);        // 128*HW_*52 u32 (+pad)
  float* diib = (float*)(cwpk + (size_t)128 * HW_ * CWST + 64);  // 128*HW_ f32

  // K1: QKV GEMM (MFMA split-bf16) + per-head l2norm + scatter
  qkv_mfma<<<dim3(392, 3), 256, 0, stream>>>(x, qkv_w, qn, kc, vv);
  // K2a: dense correlation (bf16 hi/lo packed) + dii, batched LDS reads
  corr_dense<<<dim3(1792), 256, 0, stream>>>(qn, kc, pos1, cwpk, diib);
  // K2b: window attention from precomputed corr
  attn_mfma<<<dim3(8192), 64, 0, stream>>>(qn, vv, cwpk, diib, pos2, out);
  // K3: output projection, in-place
  gemm128<1><<<dim3(392), 256, 0, stream>>>(out, proj_w, proj_b, nullptr, nullptr, nullptr, out);
}

// Round 20
// 189.782 us; speedup vs baseline: 1.0972x; 1.0972x over previous
//
#include <hip/hip_runtime.h>
#include <math.h>

// Problem constants (B=2, T=8, H=W=56, C=128, heads=8, hd=16, WS=7, nh=nw=8)
constexpr int H_   = 56;
constexpr int HW_  = 56 * 56;          // 3136
constexpr int NPIX = 8 * HW_;          // 25088 (per batch)
constexpr int SLAB = 128 * HW_ * 16;   // floats per q/k/v buffer
constexpr int CWST = 52;               // cwpk row stride (u32)

typedef __attribute__((ext_vector_type(8))) short bf16x8;
typedef __attribute__((ext_vector_type(4))) float f32x4;
typedef __attribute__((ext_vector_type(4))) unsigned int u32x4;

__device__ __forceinline__ unsigned short f2bf(float x) {
  unsigned int u = __float_as_uint(x);
  unsigned int r = (u + 0x7fffu + ((u >> 16) & 1u)) >> 16;
  return (unsigned short)r;
}
__device__ __forceinline__ float bf2f(unsigned short h) {
  return __uint_as_float(((unsigned int)h) << 16);
}

// ---------------------------------------------------------------------------
// pack_f32bf: stream-convert f32 -> packed (bf16_hi | bf16_lo<<16) u32.
// Used once for X (25.7MB) and qkv_w (197KB); removes ALL conversion from the
// qkv hot loop (R19's 143us regression = inline-conversion serialization).
// ---------------------------------------------------------------------------
__global__ __launch_bounds__(256) void pack_f32bf(
    const float* __restrict__ src, unsigned int* __restrict__ dst, int n4)
{
  int i = blockIdx.x * 256 + threadIdx.x;
  const int stride = gridDim.x * 256;
  for (; i < n4; i += stride) {
    f32x4 v = *(const f32x4*)(src + (size_t)i * 4);
    unsigned int pk[4];
#pragma unroll
    for (int e = 0; e < 4; ++e) {
      unsigned short hb = f2bf(v[e]);
      unsigned short lb = f2bf(v[e] - bf2f(hb));
      pk[e] = (unsigned)hb | ((unsigned)lb << 16);
    }
    *(u32x4*)(dst + (size_t)i * 4) = *(const u32x4*)pk;
  }
}

// ---------------------------------------------------------------------------
// K1 v3: QKV GEMM via MFMA split-bf16 from PRE-PACKED operands.
//  - staging: 8 batched u32x4 copies global->LDS (no conversion).
//  - B-fragments: 8 batched u32x4 loads from pre-packed W + register split.
//  - A-fragments: batched LDS u32x4 loads + register split.
//  - Epilogue: per-(pixel,head) l2norm via shfl_xor(1,2,4,8) (C/D col dim =
//    head's 16 channels), scatter to (BT, HW, 16). Math identical to R19
//    (passed, absmax 4.9e-4).
// ---------------------------------------------------------------------------
__global__ __launch_bounds__(256) void qkv_mfma(
    const unsigned int* __restrict__ Xp, const unsigned int* __restrict__ Wpk,
    float* __restrict__ Yq, float* __restrict__ Yk, float* __restrict__ Yv)
{
  __shared__ unsigned int xS[128 * 68];   // 34816 B
  const int tid = threadIdx.x;
  const int wave = tid >> 6, lane = tid & 63;
  const int lg = lane >> 4, lr = lane & 15;
  const int wm = wave >> 1, wn = wave & 1;
  const int mbase = blockIdx.x * 128;
  const int nt = blockIdx.y;
  const unsigned int* Wp = Wpk + (size_t)nt * (128 * 128);
  float* Ybase = (nt == 0) ? Yq : ((nt == 1) ? Yk : Yv);

  f32x4 acc[4][4];
#pragma unroll
  for (int mt = 0; mt < 4; ++mt)
#pragma unroll
    for (int ct = 0; ct < 4; ++ct) acc[mt][ct] = (f32x4)0.f;

#pragma unroll
  for (int kh = 0; kh < 2; ++kh) {
    if (kh) __syncthreads();            // xS reuse
    // ---- stage X k-half: 8 batched u32x4 copies ----
    u32x4 L[8];
#pragma unroll
    for (int c = 0; c < 8; ++c) {
      const int chunk = c * 256 + tid;
      const int row = chunk >> 4;
      const int cc = chunk & 15;
      L[c] = *(const u32x4*)(Xp + (size_t)(mbase + row) * 128 + kh * 64 + cc * 4);
    }
#pragma unroll
    for (int c = 0; c < 8; ++c) {
      const int chunk = c * 256 + tid;
      const int row = chunk >> 4;
      const int cc = chunk & 15;
      *(u32x4*)&xS[row * 68 + cc * 4] = L[c];
    }
    __syncthreads();

#pragma unroll
    for (int ks2 = 0; ks2 < 2; ++ks2) {
      // ---- batched raw loads: A from LDS, B from packed W (L2-hot) ----
      u32x4 ar[4][2], br[4][2];
#pragma unroll
      for (int mt = 0; mt < 4; ++mt) {
        const unsigned int* s = &xS[(wm * 64 + mt * 16 + lr) * 68 + ks2 * 32 + lg * 8];
        ar[mt][0] = *(const u32x4*)s;
        ar[mt][1] = *(const u32x4*)(s + 4);
      }
#pragma unroll
      for (int ct = 0; ct < 4; ++ct) {
        const unsigned int* ws = Wp + (size_t)(wn * 64 + ct * 16 + lr) * 128 + kh * 64 + ks2 * 32 + lg * 8;
        br[ct][0] = *(const u32x4*)ws;
        br[ct][1] = *(const u32x4*)(ws + 4);
      }
      // ---- register hi/lo split ----
      bf16x8 ah[4], al[4], bh[4], bl[4];
#pragma unroll
      for (int mt = 0; mt < 4; ++mt) {
        unsigned int u0[8];
        *(u32x4*)&u0[0] = ar[mt][0];
        *(u32x4*)&u0[4] = ar[mt][1];
        union { u32x4 uu; bf16x8 ss; } Hh, Ll;
#pragma unroll
        for (int p = 0; p < 4; ++p) {
          Hh.uu[p] = (u0[2*p] & 0xffffu) | (u0[2*p+1] << 16);
          Ll.uu[p] = (u0[2*p] >> 16) | (u0[2*p+1] & 0xffff0000u);
        }
        ah[mt] = Hh.ss;
        al[mt] = Ll.ss;
      }
#pragma unroll
      for (int ct = 0; ct < 4; ++ct) {
        unsigned int u0[8];
        *(u32x4*)&u0[0] = br[ct][0];
        *(u32x4*)&u0[4] = br[ct][1];
        union { u32x4 uu; bf16x8 ss; } Hh, Ll;
#pragma unroll
        for (int p = 0; p < 4; ++p) {
          Hh.uu[p] = (u0[2*p] & 0xffffu) | (u0[2*p+1] << 16);
          Ll.uu[p] = (u0[2*p] >> 16) | (u0[2*p+1] & 0xffff0000u);
        }
        bh[ct] = Hh.ss;
        bl[ct] = Ll.ss;
      }
      // ---- MFMA 3-product ----
#pragma unroll
      for (int mt = 0; mt < 4; ++mt) {
#pragma unroll
        for (int ct = 0; ct < 4; ++ct) {
          acc[mt][ct] = __builtin_amdgcn_mfma_f32_16x16x32_bf16(ah[mt], bh[ct], acc[mt][ct], 0, 0, 0);
          acc[mt][ct] = __builtin_amdgcn_mfma_f32_16x16x32_bf16(ah[mt], bl[ct], acc[mt][ct], 0, 0, 0);
          acc[mt][ct] = __builtin_amdgcn_mfma_f32_16x16x32_bf16(al[mt], bh[ct], acc[mt][ct], 0, 0, 0);
        }
      }
    }
  }

  // ---- epilogue: l2norm per (pixel, head) + scatter to (BT, HW, 16) ----
#pragma unroll
  for (int mt = 0; mt < 4; ++mt) {
#pragma unroll
    for (int reg = 0; reg < 4; ++reg) {
      const int gpix = mbase + wm * 64 + mt * 16 + lg * 4 + reg;
      const int b = (gpix >= NPIX) ? 1 : 0;
      const int rem = gpix - b * NPIX;
      const int t = rem / HW_;
      const int sp = rem - t * HW_;
#pragma unroll
      for (int ct = 0; ct < 4; ++ct) {
        float val = acc[mt][ct][reg];
        float ss = val * val;
        ss += __shfl_xor(ss, 1);
        ss += __shfl_xor(ss, 2);
        ss += __shfl_xor(ss, 4);
        ss += __shfl_xor(ss, 8);
        float r = 1.f;
        if (nt < 2) r = 1.f / fmaxf(sqrtf(ss), 1e-12f);
        const int btq = (b * 8 + wn * 4 + ct) * 8 + t;
        Ybase[((size_t)btq * HW_ + sp) * 16 + lr] = val * r;
      }
    }
  }
}

// ---------------------------------------------------------------------------
// GEMM (fp32): K3 proj only (in-place row-disjoint, bias).
// ---------------------------------------------------------------------------
template <int MODE>
__global__ __launch_bounds__(256, 3) void gemm128(
    const float* X, const float* __restrict__ Wt, const float* __restrict__ bias,
    float* __restrict__ Yq, float* __restrict__ Yk, float* __restrict__ Yv,
    float* Yout)
{
  __shared__ float xT[32][132];
  __shared__ float wT[32][132];
  const int tid = threadIdx.x;
  const int tx = tid & 15, ty = tid >> 4;
  const int mbase = blockIdx.x * 128;
  const float* Wp = Wt;

  float acc[8][8];
#pragma unroll
  for (int i = 0; i < 8; ++i)
#pragma unroll
    for (int j = 0; j < 8; ++j) acc[i][j] = 0.f;

  const int srow = tid >> 3;
  const int scol = (tid & 7) * 4;

  for (int kt = 0; kt < 4; ++kt) {
    if (kt) __syncthreads();
#pragma unroll
    for (int p = 0; p < 4; ++p) {
      int r = p * 32 + srow;
      float4 vx = *(const float4*)&X [(size_t)(mbase + r) * 128 + kt * 32 + scol];
      float4 vw = *(const float4*)&Wp[(size_t)r * 128 + kt * 32 + scol];
      xT[scol + 0][r] = vx.x; xT[scol + 1][r] = vx.y; xT[scol + 2][r] = vx.z; xT[scol + 3][r] = vx.w;
      wT[scol + 0][r] = vw.x; wT[scol + 1][r] = vw.y; wT[scol + 2][r] = vw.z; wT[scol + 3][r] = vw.w;
    }
    __syncthreads();
#pragma unroll 4
    for (int c = 0; c < 32; ++c) {
      float4 a0 = *(const float4*)&xT[c][tx * 4];
      float4 a1 = *(const float4*)&xT[c][64 + tx * 4];
      float4 b0 = *(const float4*)&wT[c][ty * 4];
      float4 b1 = *(const float4*)&wT[c][64 + ty * 4];
      float a[8] = {a0.x, a0.y, a0.z, a0.w, a1.x, a1.y, a1.z, a1.w};
      float b[8] = {b0.x, b0.y, b0.z, b0.w, b1.x, b1.y, b1.z, b1.w};
#pragma unroll
      for (int i = 0; i < 8; ++i)
#pragma unroll
        for (int j = 0; j < 8; ++j) acc[i][j] += a[i] * b[j];
    }
  }

  {
    float4 bb0 = *(const float4*)&bias[ty * 4];
    float4 bb1 = *(const float4*)&bias[64 + ty * 4];
#pragma unroll
    for (int i = 0; i < 8; ++i) {
      int gpix = mbase + ((i < 4) ? (tx * 4 + i) : (64 + tx * 4 + (i - 4)));
      float* dst = Yout + (size_t)gpix * 128;
      *(float4*)&dst[ty * 4]      = make_float4(acc[i][0]+bb0.x, acc[i][1]+bb0.y, acc[i][2]+bb0.z, acc[i][3]+bb0.w);
      *(float4*)&dst[64 + ty * 4] = make_float4(acc[i][4]+bb1.x, acc[i][5]+bb1.y, acc[i][6]+bb1.z, acc[i][7]+bb1.w);
    }
  }
}

// ---------------------------------------------------------------------------
// K2a v5 (R18 verbatim): dense correlation with batched LDS reads.
// ---------------------------------------------------------------------------
__global__ __launch_bounds__(256) void corr_dense(
    const float* __restrict__ qn, const float* __restrict__ kn,
    const float* __restrict__ pos1,
    unsigned int* __restrict__ cwpk, float* __restrict__ diib)
{
  __shared__ float kS[10 * 1120];    // 10 rows x 56 px x 20 floats = 44800 B
  const int bid = blockIdx.x;        // 1792 = 8 xcd * 16 bt * 14 strips
  const int xcd = bid & 7;
  const int j = bid >> 3;            // 0..223
  const int g = j / 14;
  const int strip = j - g * 14;
  const int bt = xcd * 16 + g;
  const int h0 = strip * 4;
  const int t = bt & 7;
  const int btk = bt - t + ((t < 7) ? (t + 1) : 7);
  const float* qb = qn + (size_t)bt  * (HW_ * 16);
  const float* kb = kn + (size_t)btk * (HW_ * 16);
  const int tid = threadIdx.x;

  for (int idx = tid; idx < 2240; idx += 256) {
    int r = idx / 224;
    int c = idx - r * 224;
    int hh = h0 - 3 + r;
    f32x4 v = (f32x4)0.f;
    if ((unsigned)hh < 56u)
      v = *(const f32x4*)(kb + (size_t)(hh * 56) * 16 + c * 4);
    *(f32x4*)&kS[r * 1120 + (c >> 2) * 20 + (c & 3) * 4] = v;
  }
  __syncthreads();

  if (tid < 224) {
    const int py = tid / 56;
    const int h = h0 + py;
    const int w = tid - py * 56;
    const f32x4* qp = (const f32x4*)(qb + (size_t)(h * 56 + w) * 16);
    f32x4 q0 = qp[0], q1 = qp[1], q2 = qp[2], q3 = qp[3];
    const int ridx = (h >> 3) * 7 + (w >> 3);
    const float* p1r = pos1 + ridx * 49;
    unsigned int* outr = cwpk + (size_t)(bt * HW_ + h * 56 + w) * CWST;
    float dii = 0.f;
#pragma unroll
    for (int d4 = 0; d4 < 12; ++d4) {
      f32x4 kv[4][4];
#pragma unroll
      for (int e = 0; e < 4; ++e) {
        const int d = d4 * 4 + e;
        const int du = d / 7, dv = d % 7;
        const int ww = w + dv - 3;
        const int wc = ww < 0 ? 0 : (ww > 55 ? 55 : ww);
        const float* kp = &kS[(py + du) * 1120 + wc * 20];
        kv[e][0] = *(const f32x4*)kp;
        kv[e][1] = *(const f32x4*)(kp + 4);
        kv[e][2] = *(const f32x4*)(kp + 8);
        kv[e][3] = *(const f32x4*)(kp + 12);
      }
      unsigned int pk[4];
#pragma unroll
      for (int e = 0; e < 4; ++e) {
        const int d = d4 * 4 + e;
        const int dv = d % 7;
        const int ww = w + dv - 3;
        f32x4 a4 = q0 * kv[e][0] + q1 * kv[e][1] + q2 * kv[e][2] + q3 * kv[e][3];
        float pd = (a4.x + a4.y) + (a4.z + a4.w);
        pd = ((unsigned)ww < 56u) ? pd : 0.f;
        const float val = pd + p1r[d];
        dii += val * val;
        unsigned short hb = f2bf(val);
        unsigned short lb = f2bf(val - bf2f(hb));
        pk[e] = (unsigned)hb | ((unsigned)lb << 16);
      }
      *(u32x4*)(outr + d4 * 4) = *(const u32x4*)pk;
    }
    {
      const int ww = w + 3;
      const int wc = ww > 55 ? 55 : ww;
      const float* kp = &kS[(py + 6) * 1120 + wc * 20];
      f32x4 k0 = *(const f32x4*)kp;
      f32x4 k1 = *(const f32x4*)(kp + 4);
      f32x4 k2 = *(const f32x4*)(kp + 8);
      f32x4 k3 = *(const f32x4*)(kp + 12);
      f32x4 a4 = q0 * k0 + q1 * k1 + q2 * k2 + q3 * k3;
      float pd = (a4.x + a4.y) + (a4.z + a4.w);
      pd = ((unsigned)ww < 56u) ? pd : 0.f;
      const float val = pd + p1r[48];
      dii += val * val;
      unsigned short hb = f2bf(val);
      unsigned short lb = f2bf(val - bf2f(hb));
      outr[48] = (unsigned)hb | ((unsigned)lb << 16);
    }
    diib[bt * HW_ + h * 56 + w] = dii;
  }
}

// ---------------------------------------------------------------------------
// K2b: MFMA window attention (R13/R18 verbatim).
// ---------------------------------------------------------------------------
__global__ __launch_bounds__(64, 2) void attn_mfma(
    const float* __restrict__ qn, const float* __restrict__ vv,
    const unsigned int* __restrict__ cwpk, const float* __restrict__ diib,
    const float* __restrict__ pos2, float* __restrict__ mid)
{
  __shared__ __align__(16) unsigned char smem[7808];
  unsigned short* Pb   = (unsigned short*)smem;       // [49][72] bf16 (7056 B)
  float*          mi_s = (float*)(smem + 7104);       // [49]
  float*          scm  = (float*)(smem + 7300);       // [49]
  float*          sca  = (float*)(smem + 7500);       // [49]

  const int lane = threadIdx.x;
  const int lg = lane >> 4;
  const int lr = lane & 15;
  const int bid = blockIdx.x;
  const int xcd = bid & 7;
  const int j = bid >> 3;
  const int bt = xcd * 16 + (j >> 6);
  const int win = j & 63;
  const int wy = win >> 3;
  const int wx = win & 7;
  const float* qb = qn + (size_t)bt * (HW_ * 16);
  const float* vb = vv + (size_t)bt * (HW_ * 16);
  const unsigned int* cwb = cwpk + (size_t)bt * HW_ * CWST;
  const float* dib = diib + (size_t)bt * HW_;

  const bool rowok = (lane < 49);
  const int il = rowok ? lane : 48;

  float xv[2][8];
#pragma unroll
  for (int ks = 0; ks < 2; ++ks) {
#pragma unroll
    for (int e = 0; e < 8; ++e) {
      int k = ks * 32 + lg * 8 + e;
      int kc2 = (k < 49) ? k : 0;
      int ka = (kc2 * 37) >> 8;
      int kb2 = kc2 - ka * 7;
      float x = vb[(size_t)((ka * 8 + wy) * 56 + (kb2 * 8 + wx)) * 16 + lr];
      xv[ks][e] = (k < 49) ? x : 0.f;
    }
  }

  {
    const int ia = (il * 37) >> 8;
    const int ib = il - ia * 7;
    float dii = dib[(ia * 8 + wy) * 56 + (ib * 8 + wx)];
    float md = dii;
#pragma unroll
    for (int o = 32; o >= 1; o >>= 1) md = fmaxf(md, __shfl_xor(md, o));
    if (rowok) mi_s[il] = sqrtf(dii * md);
  }

  bf16x8 ah[4][2], al[4][2];
#pragma unroll
  for (int half = 0; half < 2; ++half) {
    u32x4 raw[2][2][2];
#pragma unroll
    for (int u = 0; u < 2; ++u) {
      const int tt2 = half * 2 + u;
      const int row = tt2 * 16 + lr;
      const int rowc = (row < 49) ? row : 0;
      const int a2 = (rowc * 37) >> 8;
      const int b3 = rowc - a2 * 7;
      const unsigned int* src = cwb + (size_t)((a2 * 8 + wy) * 56 + (b3 * 8 + wx)) * CWST;
#pragma unroll
      for (int ks = 0; ks < 2; ++ks) {
        const int cb = ks * 32 + lg * 8;
        raw[u][ks][0] = *(const u32x4*)(src + cb);
        raw[u][ks][1] = *(const u32x4*)(src + cb + 4);
      }
    }
#pragma unroll
    for (int u = 0; u < 2; ++u) {
      const int tt2 = half * 2 + u;
      const int row = tt2 * 16 + lr;
      const bool rv = (row < 49);
#pragma unroll
      for (int ks = 0; ks < 2; ++ks) {
        const int cb = ks * 32 + lg * 8;
        unsigned int u0[8];
        *(u32x4*)&u0[0] = raw[u][ks][0];
        *(u32x4*)&u0[4] = raw[u][ks][1];
#pragma unroll
        for (int e = 0; e < 8; ++e)
          if (!rv || (cb + e) >= 49) u0[e] = 0u;
        union { u32x4 uu; bf16x8 s; } Hh, Ll;
#pragma unroll
        for (int p = 0; p < 4; ++p) {
          Hh.uu[p] = (u0[2*p] & 0xffffu) | (u0[2*p+1] << 16);
          Ll.uu[p] = (u0[2*p] >> 16) | (u0[2*p+1] & 0xffff0000u);
        }
        ah[tt2][ks] = Hh.s;
        al[tt2][ks] = Ll.s;
      }
    }
  }

#pragma unroll
  for (int rt = 0; rt < 4; ++rt) {
    f32x4 C[4];
#pragma unroll
    for (int ct = 0; ct < 4; ++ct) C[ct] = (f32x4)0.f;
#pragma unroll
    for (int ks = 0; ks < 2; ++ks) {
#pragma unroll
      for (int ct = 0; ct < 4; ++ct) {
        C[ct] = __builtin_amdgcn_mfma_f32_16x16x32_bf16(ah[rt][ks], ah[ct][ks], C[ct], 0, 0, 0);
        C[ct] = __builtin_amdgcn_mfma_f32_16x16x32_bf16(ah[rt][ks], al[ct][ks], C[ct], 0, 0, 0);
        C[ct] = __builtin_amdgcn_mfma_f32_16x16x32_bf16(al[rt][ks], ah[ct][ks], C[ct], 0, 0, 0);
      }
    }
#pragma unroll
    for (int reg = 0; reg < 4; ++reg) {
      int row = rt * 16 + lg * 4 + reg;
      float m = mi_s[(row < 49) ? row : 0];
#pragma unroll
      for (int ct = 0; ct < 4; ++ct) {
        float p = __expf(C[ct][reg] - m);
        if (row < 49) Pb[row * 72 + ct * 16 + lr] = f2bf(p);
      }
    }
  }
  asm volatile("" ::: "memory");

  if (rowok) {
    const u32x4* pr = (const u32x4*)(Pb + il * 72);
    unsigned int uu[28];
#pragma unroll
    for (int w = 0; w < 7; ++w) *(u32x4*)&uu[4*w] = pr[w];
    float s = 0.f;
#pragma unroll
    for (int w = 0; w < 24; ++w)
      s += bf2f((unsigned short)(uu[w] & 0xffffu)) + bf2f((unsigned short)(uu[w] >> 16));
    s += bf2f((unsigned short)(uu[24] & 0xffffu));
    scm[il] = 0.5f / s;
  }

  bf16x8 vfh[2], vfl[2];
#pragma unroll
  for (int ks = 0; ks < 2; ++ks) {
    union { u32x4 u; bf16x8 s; } Hh, Ll;
#pragma unroll
    for (int p = 0; p < 4; ++p) {
      unsigned short h0 = f2bf(xv[ks][2*p]);
      unsigned short h1 = f2bf(xv[ks][2*p+1]);
      unsigned short l0 = f2bf(xv[ks][2*p]   - bf2f(h0));
      unsigned short l1 = f2bf(xv[ks][2*p+1] - bf2f(h1));
      Hh.u[p] = (unsigned int)h0 | ((unsigned int)h1 << 16);
      Ll.u[p] = (unsigned int)l0 | ((unsigned int)l1 << 16);
    }
    vfh[ks] = Hh.s;
    vfl[ks] = Ll.s;
  }

  f32x4 om[4];
#pragma unroll
  for (int rt = 0; rt < 4; ++rt) om[rt] = (f32x4)0.f;
#pragma unroll
  for (int ks = 0; ks < 2; ++ks) {
#pragma unroll
    for (int rt = 0; rt < 4; ++rt) {
      int row = rt * 16 + lr;
      int rowc = (row < 49) ? row : 0;
      bf16x8 pa = *(const bf16x8*)(Pb + rowc * 72 + ks * 32 + lg * 8);
      om[rt] = __builtin_amdgcn_mfma_f32_16x16x32_bf16(pa, vfh[ks], om[rt], 0, 0, 0);
      om[rt] = __builtin_amdgcn_mfma_f32_16x16x32_bf16(pa, vfl[ks], om[rt], 0, 0, 0);
    }
  }
  asm volatile("s_waitcnt lgkmcnt(0)" ::: "memory");

  bf16x8 qf[4];
#pragma unroll
  for (int half = 0; half < 2; ++half) {
    f32x4 qa_[2], qb_[2], pa_[2], pb_[2];
#pragma unroll
    for (int u = 0; u < 2; ++u) {
      const int tt2 = half * 2 + u;
      int row = tt2 * 16 + lr;
      int rowc = (row < 49) ? row : 0;
      int a2 = (rowc * 37) >> 8;
      int b3 = rowc - a2 * 7;
      const int co = (lg & 1) * 8;
      const float* qsrc = qb + (size_t)((a2 * 8 + wy) * 56 + (b3 * 8 + wx)) * 16 + co;
      qa_[u] = *(const f32x4*)qsrc;
      qb_[u] = *(const f32x4*)(qsrc + 4);
      const float* p2 = pos2 + rowc * 16 + co;
      pa_[u] = *(const f32x4*)p2;
      pb_[u] = *(const f32x4*)(p2 + 4);
    }
#pragma unroll
    for (int u = 0; u < 2; ++u) {
      const int tt2 = half * 2 + u;
      int row = tt2 * 16 + lr;
      f32x4 w0 = qa_[u] + pa_[u], w1 = qb_[u] + pb_[u];
      float ws[8] = {w0.x, w0.y, w0.z, w0.w, w1.x, w1.y, w1.z, w1.w};
      const bool zv = (row >= 49) || (lg >= 2);
      union { u32x4 u4; bf16x8 s; } Q;
#pragma unroll
      for (int p = 0; p < 4; ++p) {
        unsigned int v = (unsigned)f2bf(ws[2*p]) | ((unsigned)f2bf(ws[2*p+1]) << 16);
        Q.u4[p] = zv ? 0u : v;
      }
      qf[tt2] = Q.s;
    }
  }

#pragma unroll
  for (int rt = 0; rt < 4; ++rt) {
    f32x4 Ca[4];
#pragma unroll
    for (int ct = 0; ct < 4; ++ct) Ca[ct] = (f32x4)0.f;
#pragma unroll
    for (int ct = 0; ct < 4; ++ct)
      Ca[ct] = __builtin_amdgcn_mfma_f32_16x16x32_bf16(qf[rt], qf[ct], Ca[ct], 0, 0, 0);
#pragma unroll
    for (int reg = 0; reg < 4; ++reg) {
      int row = rt * 16 + lg * 4 + reg;
#pragma unroll
      for (int ct = 0; ct < 4; ++ct) {
        float p = __expf(Ca[ct][reg]);
        if (row < 49) Pb[row * 72 + ct * 16 + lr] = f2bf(p);
      }
    }
  }
  asm volatile("" ::: "memory");

  if (rowok) {
    const u32x4* pr = (const u32x4*)(Pb + il * 72);
    unsigned int uu[28];
#pragma unroll
    for (int w = 0; w < 7; ++w) *(u32x4*)&uu[4*w] = pr[w];
    float s = 0.f;
#pragma unroll
    for (int w = 0; w < 24; ++w)
      s += bf2f((unsigned short)(uu[w] & 0xffffu)) + bf2f((unsigned short)(uu[w] >> 16));
    s += bf2f((unsigned short)(uu[24] & 0xffffu));
    sca[il] = 0.5f / s;
  }

  f32x4 oa[4];
#pragma unroll
  for (int rt = 0; rt < 4; ++rt) oa[rt] = (f32x4)0.f;
#pragma unroll
  for (int ks = 0; ks < 2; ++ks) {
#pragma unroll
    for (int rt = 0; rt < 4; ++rt) {
      int row = rt * 16 + lr;
      int rowc = (row < 49) ? row : 0;
      bf16x8 pa = *(const bf16x8*)(Pb + rowc * 72 + ks * 32 + lg * 8);
      oa[rt] = __builtin_amdgcn_mfma_f32_16x16x32_bf16(pa, vfh[ks], oa[rt], 0, 0, 0);
      oa[rt] = __builtin_amdgcn_mfma_f32_16x16x32_bf16(pa, vfl[ks], oa[rt], 0, 0, 0);
    }
  }

  {
    int b = bt >> 6, e = (bt >> 3) & 7, tt = bt & 7;
    size_t obase = ((size_t)(b * NPIX + tt * HW_)) * 128 + e * 16 + lr;
#pragma unroll
    for (int rt = 0; rt < 4; ++rt) {
#pragma unroll
      for (int reg = 0; reg < 4; ++reg) {
        int row = rt * 16 + lg * 4 + reg;
        if (row < 49) {
          float o = om[rt][reg] * scm[row] + oa[rt][reg] * sca[row];
          int a2 = (row * 37) >> 8;
          int b3 = row - a2 * 7;
          mid[obase + (size_t)((a2 * 8 + wy) * 56 + (b3 * 8 + wx)) * 128] = o;
        }
      }
    }
  }
}

// ---------------------------------------------------------------------------
extern "C" void kernel_launch(void* const* d_in, const int* in_sizes, int n_in,
                              void* d_out, int out_size, void* d_ws, size_t ws_size,
                              hipStream_t stream) {
  (void)in_sizes; (void)n_in; (void)out_size; (void)ws_size;
  const float* x      = (const float*)d_in[0];
  const float* qkv_w  = (const float*)d_in[1];
  const float* proj_w = (const float*)d_in[2];
  const float* proj_b = (const float*)d_in[3];
  const float* pos1   = (const float*)d_in[4];
  const float* pos2   = (const float*)d_in[5];
  float* out = (float*)d_out;

  float* qn = (float*)d_ws;                               // SLAB f32
  float* kc = qn + SLAB;                                  // SLAB f32
  float* vv = kc + SLAB;                                  // SLAB f32
  unsigned int* cwpk = (unsigned int*)(vv + SLAB);        // 128*HW_*52 u32 (+pad)
  float* diib = (float*)(cwpk + (size_t)128 * HW_ * CWST + 64);  // 128*HW_ f32

  // Packed X and W live in the cwpk region (dead until corr_dense runs):
  unsigned int* xpk = cwpk;                               // 50176*128 u32 (25.7MB)
  unsigned int* wpk = cwpk + (size_t)50176 * 128 + 64;    // 384*128 u32

  // K0: pack X and qkv_w to bf16 hi/lo u32 (stream kernels)
  pack_f32bf<<<dim3(2048), 256, 0, stream>>>(x, xpk, 50176 * 32);
  pack_f32bf<<<dim3(48), 256, 0, stream>>>(qkv_w, wpk, 384 * 32);
  // K1: QKV GEMM (MFMA from pre-packed operands) + l2norm + scatter
  qkv_mfma<<<dim3(392, 3), 256, 0, stream>>>(xpk, wpk, qn, kc, vv);
  // K2a: dense correlation (overwrites the xpk/cwpk region)
  corr_dense<<<dim3(1792), 256, 0, stream>>>(qn, kc, pos1, cwpk, diib);
  // K2b: window attention from precomputed corr
  attn_mfma<<<dim3(8192), 64, 0, stream>>>(qn, vv, cwpk, diib, pos2, out);
  // K3: output projection, in-place
  gemm128<1><<<dim3(392), 256, 0, stream>>>(out, proj_w, proj_b, nullptr, nullptr, nullptr, out);
}